// Round 1
// baseline (193.933 us; speedup 1.0000x reference)
//
#include <hip/hip_runtime.h>
#include <hip/hip_bf16.h>

#define S_  384
#define H_  256
#define NH_ 8
#define DH_ 32
#define B_  4
#define PADK 385

// ---------------- Kernel P: fused QKV projections ----------------
// grid (48, 4, 3), block 256. Tile 32(m) x 64(n), K-tile 32.
__global__ __launch_bounds__(256) void proj_kernel(
    const float* __restrict__ query, const float* __restrict__ key, const float* __restrict__ value,
    const float* __restrict__ Wq, const float* __restrict__ bq,
    const float* __restrict__ Wk, const float* __restrict__ bk,
    const float* __restrict__ Wv, const float* __restrict__ bv,
    float* __restrict__ Qb, float* __restrict__ Kb, float* __restrict__ Vb)
{
    __shared__ __align__(16) float As[32][36];
    __shared__ __align__(16) float Bs[32][68];
    const int t = threadIdx.x;
    const int m0g = blockIdx.x * 32;
    const int n0g = blockIdx.y * 64;
    const int z = blockIdx.z;
    const float* X    = (z == 0) ? query : (z == 1 ? key : value);
    const float* W    = (z == 0) ? Wq    : (z == 1 ? Wk  : Wv);
    const float* bias = (z == 0) ? bq    : (z == 1 ? bk  : bv);
    float* Out        = (z == 0) ? Qb    : (z == 1 ? Kb  : Vb);

    const int tn = (t & 15) * 4;      // 4 output cols
    const int tm = (t >> 4) * 2;      // 2 output rows
    float acc0[4] = {0.f,0.f,0.f,0.f};
    float acc1[4] = {0.f,0.f,0.f,0.f};

    const int ar = t >> 3, ac4 = (t & 7) * 4;     // A staging: 32 rows x 32 cols
    const int brr = t >> 4, bc4 = (t & 15) * 4;   // B staging: 32 rows x 64 cols

    for (int kt = 0; kt < 8; ++kt) {
        const int k0 = kt * 32;
        float4 av  = *(const float4*)&X[(size_t)(m0g + ar) * H_ + k0 + ac4];
        float4 bv0 = *(const float4*)&W[(size_t)(k0 + brr)      * H_ + n0g + bc4];
        float4 bv1 = *(const float4*)&W[(size_t)(k0 + brr + 16) * H_ + n0g + bc4];
        *(float4*)&As[ar][ac4] = av;
        *(float4*)&Bs[brr][bc4] = bv0;
        *(float4*)&Bs[brr + 16][bc4] = bv1;
        __syncthreads();
        #pragma unroll
        for (int c = 0; c < 32; ++c) {
            const float a0 = As[tm][c], a1 = As[tm + 1][c];
            const float4 b4 = *(const float4*)&Bs[c][tn];
            acc0[0] += a0 * b4.x; acc0[1] += a0 * b4.y; acc0[2] += a0 * b4.z; acc0[3] += a0 * b4.w;
            acc1[0] += a1 * b4.x; acc1[1] += a1 * b4.y; acc1[2] += a1 * b4.z; acc1[3] += a1 * b4.w;
        }
        __syncthreads();
    }
    const float4 bi = *(const float4*)&bias[n0g + tn];
    float4 o0 = make_float4(acc0[0] + bi.x, acc0[1] + bi.y, acc0[2] + bi.z, acc0[3] + bi.w);
    float4 o1 = make_float4(acc1[0] + bi.x, acc1[1] + bi.y, acc1[2] + bi.z, acc1[3] + bi.w);
    *(float4*)&Out[(size_t)(m0g + tm)     * H_ + n0g + tn] = o0;
    *(float4*)&Out[(size_t)(m0g + tm + 1) * H_ + n0g + tn] = o1;
}

// ---------------- Kernel QW: qW[b,q,h,e] = sum_d Q[b,q,hd]*Wr[e,hd]; qb = Q . br ----
// grid (96, 8), block 256 (thread = e).
__global__ __launch_bounds__(256) void qw_kernel(
    const float* __restrict__ Qb, const float* __restrict__ Wr, const float* __restrict__ br,
    float* __restrict__ qW, float* __restrict__ qb)
{
    __shared__ __align__(16) float Qs[16][36];
    const int t = threadIdx.x;                // e index
    const int m0 = blockIdx.x * 16;           // row block over b*S+q
    const int h = blockIdx.y;

    float4 wr4[8];
    #pragma unroll
    for (int j = 0; j < 8; ++j)
        wr4[j] = *(const float4*)&Wr[(size_t)t * H_ + h * DH_ + j * 4];

    if (t < 128) {
        const int r = t >> 3, d4 = (t & 7) * 4;
        *(float4*)&Qs[r][d4] = *(const float4*)&Qb[(size_t)(m0 + r) * H_ + h * DH_ + d4];
    }
    __syncthreads();

    #pragma unroll 4
    for (int r = 0; r < 16; ++r) {
        float acc = 0.f;
        #pragma unroll
        for (int j = 0; j < 8; ++j) {
            const float4 qv = *(const float4*)&Qs[r][j * 4];
            acc += qv.x * wr4[j].x + qv.y * wr4[j].y + qv.z * wr4[j].z + qv.w * wr4[j].w;
        }
        qW[(size_t)((m0 + r) * NH_ + h) * H_ + t] = acc;
    }
    if (t < 16) {
        float s = 0.f;
        #pragma unroll
        for (int d = 0; d < 32; ++d) s += Qs[t][d] * br[h * DH_ + d];
        qb[(m0 + t) * NH_ + h] = s;
    }
}

// ---------------- Kernel B: fused scores + mask + softmax + PV ----------------
// grid 1536 (one WG per (b,q)), block 256 = 4 waves.
__global__ __launch_bounds__(256) void attn_kernel(
    const float* __restrict__ rpe, const float* __restrict__ Qb, const float* __restrict__ Kb,
    const float* __restrict__ Vb, const float* __restrict__ qW, const float* __restrict__ qb,
    const int* __restrict__ seq_len, const int* __restrict__ lex_num,
    float* __restrict__ out)
{
    __shared__ float sc[NH_ * PADK];
    const int blk = blockIdx.x;
    const int b = blk / S_;
    const int q = blk - b * S_;
    const int t = threadIdx.x;
    const int lane = t & 63;
    const int wave = t >> 6;
    int limit = seq_len[b] + lex_num[b];
    limit = limit < 0 ? 0 : (limit > S_ ? S_ : limit);
    const size_t rowQ = (size_t)(b * S_ + q);

    if (limit == 0) {
        // all keys masked -> softmax over uniform -1e15 -> exactly 1/S each
        float acc = 0.f;
        const float* vb = Vb + (size_t)b * S_ * H_ + t;
        for (int k = 0; k < S_; ++k) acc += vb[(size_t)k * H_];
        out[rowQ * H_ + t] = acc * (1.0f / S_);
        return;
    }

    // head owned by this lane after the butterfly: bit-reversal of lane&7
    const int hrev = ((lane & 1) << 2) | (lane & 2) | ((lane >> 2) & 1);

    float4 qw4[NH_];
    #pragma unroll
    for (int h = 0; h < NH_; ++h)
        qw4[h] = *(const float4*)&qW[(rowQ * NH_ + h) * H_ + lane * 4];
    const float4 qrow4 = *(const float4*)&Qb[rowQ * H_ + lane * 4];
    const float qbv = qb[rowQ * NH_ + hrev];

    const float* rpe_base = rpe + rowQ * (size_t)S_ * H_;
    const float* K_base = Kb + (size_t)b * S_ * H_;

    for (int k = wave; k < limit; k += 4) {
        const float4 r4 = *(const float4*)&rpe_base[(size_t)k * H_ + lane * 4];
        const float4 k4 = *(const float4*)&K_base[(size_t)k * H_ + lane * 4];
        float facc[NH_];
        #pragma unroll
        for (int h = 0; h < NH_; ++h)
            facc[h] = r4.x * qw4[h].x + r4.y * qw4[h].y + r4.z * qw4[h].z + r4.w * qw4[h].w;
        float ac = k4.x * qrow4.x + k4.y * qrow4.y + k4.z * qrow4.z + k4.w * qrow4.w;

        // phase A: 8 accs -> 1 across each 8-lane group (exchange-halves butterfly)
        {   const bool hi = (lane & 1) != 0;
            #pragma unroll
            for (int i = 0; i < 4; ++i) {
                const float send = hi ? facc[i] : facc[i + 4];
                const float keep = hi ? facc[i + 4] : facc[i];
                facc[i] = keep + __shfl_xor(send, 1, 64);
            }
        }
        {   const bool hi = (lane & 2) != 0;
            #pragma unroll
            for (int i = 0; i < 2; ++i) {
                const float send = hi ? facc[i] : facc[i + 2];
                const float keep = hi ? facc[i + 2] : facc[i];
                facc[i] = keep + __shfl_xor(send, 2, 64);
            }
        }
        {   const bool hi = (lane & 4) != 0;
            const float send = hi ? facc[0] : facc[1];
            const float keep = hi ? facc[1] : facc[0];
            facc[0] = keep + __shfl_xor(send, 4, 64);
        }
        // phase B: sum across the 8 groups
        facc[0] += __shfl_xor(facc[0], 8, 64);
        facc[0] += __shfl_xor(facc[0], 16, 64);
        facc[0] += __shfl_xor(facc[0], 32, 64);
        // A_C: reduce within the 8-lane head group (head = lane>>3)
        ac += __shfl_xor(ac, 1, 64);
        ac += __shfl_xor(ac, 2, 64);
        ac += __shfl_xor(ac, 4, 64);
        const float acx = __shfl(ac, hrev * 8, 64);  // fetch A_C[hrev]
        const float score = facc[0] + acx + qbv;
        if (lane < 8) sc[hrev * PADK + k] = score;
    }
    __syncthreads();

    // softmax + PV; wave handles heads 2*wave and 2*wave+1
    const int half = lane >> 5;
    const int d = lane & 31;
    for (int hh = 0; hh < 2; ++hh) {
        const int h = wave * 2 + hh;
        float s0[6];
        #pragma unroll
        for (int j = 0; j < 6; ++j) {
            const int k = lane + 64 * j;
            s0[j] = (k < limit) ? sc[h * PADK + k] : -1e15f;
        }
        float mx = s0[0];
        #pragma unroll
        for (int j = 1; j < 6; ++j) mx = fmaxf(mx, s0[j]);
        #pragma unroll
        for (int m = 1; m < 64; m <<= 1) mx = fmaxf(mx, __shfl_xor(mx, m, 64));
        float p[6]; float sum = 0.f;
        #pragma unroll
        for (int j = 0; j < 6; ++j) {
            const int k = lane + 64 * j;
            p[j] = (k < limit) ? __expf(s0[j] - mx) : 0.f;
            sum += p[j];
        }
        #pragma unroll
        for (int m = 1; m < 64; m <<= 1) sum += __shfl_xor(sum, m, 64);
        const float inv = 1.0f / sum;
        #pragma unroll
        for (int j = 0; j < 6; ++j) sc[h * PADK + lane + 64 * j] = p[j] * inv;
        __syncthreads();   // order p-stores before cross-lane LDS reads (uniform)

        float acc = 0.f;
        const float* vcol = Vb + (size_t)b * S_ * H_ + h * DH_ + d;
        #pragma unroll 2
        for (int k = half; k < limit; k += 2) {
            acc += sc[h * PADK + k] * vcol[(size_t)k * H_];
        }
        acc += __shfl_xor(acc, 32, 64);
        if (lane < 32) out[rowQ * H_ + h * DH_ + d] = acc;
    }
}

extern "C" void kernel_launch(void* const* d_in, const int* in_sizes, int n_in,
                              void* d_out, int out_size, void* d_ws, size_t ws_size,
                              hipStream_t stream)
{
    const float* key   = (const float*)d_in[0];
    const float* query = (const float*)d_in[1];
    const float* value = (const float*)d_in[2];
    const float* rpe   = (const float*)d_in[3];
    const int* seq_len = (const int*)d_in[4];
    const int* lex_num = (const int*)d_in[5];
    const float* Wk = (const float*)d_in[6];
    const float* bk = (const float*)d_in[7];
    const float* Wq = (const float*)d_in[8];
    const float* bq = (const float*)d_in[9];
    const float* Wv = (const float*)d_in[10];
    const float* bv = (const float*)d_in[11];
    const float* Wr = (const float*)d_in[12];
    const float* br = (const float*)d_in[13];

    float* w = (float*)d_ws;
    float* Qb = w;
    float* Kb = Qb + (size_t)B_ * S_ * H_;
    float* Vb = Kb + (size_t)B_ * S_ * H_;
    float* qW = Vb + (size_t)B_ * S_ * H_;
    float* qb = qW + (size_t)B_ * S_ * NH_ * H_;

    proj_kernel<<<dim3(48, 4, 3), dim3(256), 0, stream>>>(
        query, key, value, Wq, bq, Wk, bk, Wv, bv, Qb, Kb, Vb);
    qw_kernel<<<dim3(96, 8), dim3(256), 0, stream>>>(Qb, Wr, br, qW, qb);
    attn_kernel<<<dim3(1536), dim3(256), 0, stream>>>(
        rpe, Qb, Kb, Vb, qW, qb, seq_len, lex_num, (float*)d_out);
}